// Round 1
// baseline (995.847 us; speedup 1.0000x reference)
//
#include <hip/hip_runtime.h>
#include <math.h>

// CropRoi fused pipeline.
// Inputs (setup_inputs order):
// 0 img (unused), 1 out1 [2,64,64,64,64], 2 comb2 [2,128,32,32,32], 3 inputs (unused),
// 4 proposals [64,7] int32, 5 w_up[64,128], 6 b_up[64], 7 g_up[64], 8 bt_up[64],
// 9 w_b2[64,128], 10 b_b2[64], 11 g_b2[64], 12 bt_b2[64]
// Output: [64,64,6,6,6] f32.

#define EPSV 1e-5f
#define NPROP 64

// align_corners 2x upsample 12->24: pos = d*11/23 (mirrors JAX f32 arithmetic)
__device__ __forceinline__ void interp_idx(int d, int& i0, int& i1, float& w) {
    float pos = (float)(d * 11) / 23.0f;
    float f = floorf(pos);
    i0 = (int)f;
    i1 = min(i0 + 1, 11);
    w = pos - f;
}

// K1: y4[p, o(64), site(12^3)] = sum_c comb2crop[p,c,site] * w_up[o,c] + b_up[o]
// (conv1x1 commutes with the linear upsample, so conv at low res.)
__global__ __launch_bounds__(256) void k1_conv1(
    const float* __restrict__ comb2, const int* __restrict__ props,
    const float* __restrict__ w_up, const float* __restrict__ b_up,
    float* __restrict__ y4)
{
    __shared__ float wT[128 * 64];   // wT[c*64 + o]
    __shared__ float bL[64];
    const int p = blockIdx.y;
    const int tid = threadIdx.x;
    for (int i = tid; i < 8192; i += 256) {
        int c = i >> 6, o = i & 63;
        wT[i] = w_up[o * 128 + c];
    }
    if (tid < 64) bL[tid] = b_up[tid];
    __syncthreads();

    const int b  = props[p * 7 + 0];
    const int z0 = props[p * 7 + 1] >> 2;
    const int y0 = props[p * 7 + 2] >> 2;
    const int x0 = props[p * 7 + 3] >> 2;
    const int og = tid >> 6;       // 0..3 -> o in [og*16, og*16+16)
    const int sl = tid & 63;

    for (int it = 0; it < 3; ++it) {
        int site = blockIdx.x * 192 + it * 64 + sl;   // < 1728
        int z = site / 144, rem = site % 144;
        int y = rem / 12, x = rem % 12;
        const float* src = comb2 + ((((long)b * 128) * 32 + (z0 + z)) * 32 + (y0 + y)) * 32 + (x0 + x);

        float acc[16];
        #pragma unroll
        for (int j = 0; j < 16; ++j) acc[j] = bL[og * 16 + j];

        for (int c = 0; c < 128; ++c) {
            float v = src[c * 32768];
            const float4* wv = (const float4*)&wT[c * 64 + og * 16];
            float4 w0 = wv[0], w1 = wv[1], w2 = wv[2], w3 = wv[3];
            acc[0]  += v * w0.x; acc[1]  += v * w0.y; acc[2]  += v * w0.z; acc[3]  += v * w0.w;
            acc[4]  += v * w1.x; acc[5]  += v * w1.y; acc[6]  += v * w1.z; acc[7]  += v * w1.w;
            acc[8]  += v * w2.x; acc[9]  += v * w2.y; acc[10] += v * w2.z; acc[11] += v * w2.w;
            acc[12] += v * w3.x; acc[13] += v * w3.y; acc[14] += v * w3.z; acc[15] += v * w3.w;
        }
        long obase = ((long)p * 64 + og * 16) * 1728 + site;
        #pragma unroll
        for (int j = 0; j < 16; ++j) y4[obase + (long)j * 1728] = acc[j];
    }
}

// K2: per (p,c) stats of the upsampled (24^3) field -> affine a1,b1 for stage-1 IN.
__global__ __launch_bounds__(64) void k2_stats1(
    const float* __restrict__ y4, const float* __restrict__ g_up,
    const float* __restrict__ bt_up, float* __restrict__ a1, float* __restrict__ b1)
{
    __shared__ float ch[1728];
    const int c = blockIdx.x, p = blockIdx.y;
    const int tid = threadIdx.x;
    const float* src = y4 + ((long)p * 64 + c) * 1728;
    for (int i = tid; i < 1728; i += 64) ch[i] = src[i];
    __syncthreads();

    float sum = 0.f, sq = 0.f;
    for (int s = tid; s < 13824; s += 64) {
        int z = s / 576, rem = s % 576;
        int y = rem / 24, x = rem % 24;
        int iz0, iz1, iy0, iy1, ix0, ix1; float wz, wy, wx;
        interp_idx(z, iz0, iz1, wz);
        interp_idx(y, iy0, iy1, wy);
        interp_idx(x, ix0, ix1, wx);
        float v00 = ch[iz0*144 + iy0*12 + ix0] * (1.f - wx) + ch[iz0*144 + iy0*12 + ix1] * wx;
        float v01 = ch[iz0*144 + iy1*12 + ix0] * (1.f - wx) + ch[iz0*144 + iy1*12 + ix1] * wx;
        float v10 = ch[iz1*144 + iy0*12 + ix0] * (1.f - wx) + ch[iz1*144 + iy0*12 + ix1] * wx;
        float v11 = ch[iz1*144 + iy1*12 + ix0] * (1.f - wx) + ch[iz1*144 + iy1*12 + ix1] * wx;
        float v0 = v00 * (1.f - wy) + v01 * wy;
        float v1 = v10 * (1.f - wy) + v11 * wy;
        float u  = v0  * (1.f - wz) + v1  * wz;
        sum += u; sq += u * u;
    }
    #pragma unroll
    for (int m = 32; m >= 1; m >>= 1) { sum += __shfl_xor(sum, m); sq += __shfl_xor(sq, m); }
    if (tid == 0) {
        float mean = sum / 13824.0f;
        float var  = fmaxf(sq / 13824.0f - mean * mean, 0.0f);
        float r = rsqrtf(var + EPSV);
        float a = g_up[c] * r;
        a1[p * 64 + c] = a;
        b1[p * 64 + c] = bt_up[c] - mean * a;
    }
}

// K3: fused conv2 + stage-2 stats + per-window max/min.
// Block = (zw slab, p). Tiles of 128 sites (= 2 pool windows), LDS-staged 128ch x 128sites.
__global__ __launch_bounds__(256) void k3_conv2(
    const float* __restrict__ y4, const float* __restrict__ out1,
    const int* __restrict__ props,
    const float* __restrict__ a1, const float* __restrict__ b1,
    const float* __restrict__ w_b2, const float* __restrict__ b_b2,
    float* __restrict__ s2sum, float* __restrict__ s2sq,
    float* __restrict__ wmaxg, float* __restrict__ wming)
{
    __shared__ float w2T[128 * 64];     // w2T[k*64 + o]
    __shared__ float Xin[128 * 128];    // Xin[k*128 + site]
    __shared__ float a1L[64], b1L[64], bL[64];
    const int zw = blockIdx.x, p = blockIdx.y;
    const int tid = threadIdx.x;

    for (int i = tid; i < 8192; i += 256) {
        int k = i >> 6, o = i & 63;
        w2T[i] = w_b2[o * 128 + k];
    }
    if (tid < 64) {
        a1L[tid] = a1[p * 64 + tid];
        b1L[tid] = b1[p * 64 + tid];
        bL[tid]  = b_b2[tid];
    }
    __syncthreads();

    const int bidx = props[p * 7 + 0];
    const int z2 = props[p * 7 + 1] >> 1;
    const int y2 = props[p * 7 + 2] >> 1;
    const int x2 = props[p * 7 + 3] >> 1;
    const float* y4p = y4 + (long)p * 64 * 1728;

    // Phase-A identity: site within tile -> (window-half, 4x4x4 coords)
    const int siteA = tid & 127, half = tid >> 7;
    const int whA = siteA >> 6, widxA = siteA & 63;
    const int zlA = widxA >> 4, ylA = (widxA >> 2) & 3, xlA = widxA & 3;
    const int zgA = zw * 4 + zlA;
    int iz0, iz1; float wz; interp_idx(zgA, iz0, iz1, wz);

    // Phase-B identity: 8 o2 x 4 sites per thread
    const int o2g = tid >> 5, sg = tid & 31;

    float localS[8] = {0,0,0,0,0,0,0,0};
    float localQ[8] = {0,0,0,0,0,0,0,0};

    for (int tile = 0; tile < 18; ++tile) {
        // ---- Phase A: fill Xin (128 channels x 128 sites) ----
        {
            int winA = tile * 2 + whA;
            int ywA = winA / 6, xwA = winA % 6;
            int yg = ywA * 4 + ylA, xg = xwA * 4 + xlA;
            if (half == 0) {
                int iy0, iy1, ix0, ix1; float wy, wx;
                interp_idx(yg, iy0, iy1, wy);
                interp_idx(xg, ix0, ix1, wx);
                float wz0 = 1.f - wz, wy0 = 1.f - wy, wx0 = 1.f - wx;
                float w000 = wz0*wy0*wx0, w001 = wz0*wy0*wx, w010 = wz0*wy*wx0, w011 = wz0*wy*wx;
                float w100 = wz*wy0*wx0,  w101 = wz*wy0*wx,  w110 = wz*wy*wx0,  w111 = wz*wy*wx;
                int o000 = iz0*144 + iy0*12 + ix0, o001 = iz0*144 + iy0*12 + ix1;
                int o010 = iz0*144 + iy1*12 + ix0, o011 = iz0*144 + iy1*12 + ix1;
                int o100 = iz1*144 + iy0*12 + ix0, o101 = iz1*144 + iy0*12 + ix1;
                int o110 = iz1*144 + iy1*12 + ix0, o111 = iz1*144 + iy1*12 + ix1;
                for (int c = 0; c < 64; ++c) {
                    const float* chp = y4p + c * 1728;
                    float u = w000*chp[o000] + w001*chp[o001] + w010*chp[o010] + w011*chp[o011]
                            + w100*chp[o100] + w101*chp[o101] + w110*chp[o110] + w111*chp[o111];
                    Xin[c * 128 + siteA] = fmaxf(a1L[c] * u + b1L[c], 0.0f);
                }
            } else {
                const float* o1p = out1 + ((((long)bidx * 64) * 64 + (z2 + zgA)) * 64 + (y2 + yg)) * 64 + (x2 + xg);
                for (int c = 0; c < 64; ++c) {
                    Xin[(64 + c) * 128 + siteA] = o1p[(long)c * 262144];
                }
            }
        }
        __syncthreads();

        // ---- Phase B: GEMM tile (64 o2 x 128 sites), 8 o2 x 4 sites per thread ----
        float acc[8][4];
        #pragma unroll
        for (int j = 0; j < 8; ++j)
            #pragma unroll
            for (int i = 0; i < 4; ++i) acc[j][i] = 0.f;

        for (int k = 0; k < 128; ++k) {
            float4 xv = *(const float4*)&Xin[k * 128 + sg * 4];
            float4 wa = *(const float4*)&w2T[k * 64 + o2g * 8];
            float4 wb = *(const float4*)&w2T[k * 64 + o2g * 8 + 4];
            acc[0][0] += wa.x*xv.x; acc[0][1] += wa.x*xv.y; acc[0][2] += wa.x*xv.z; acc[0][3] += wa.x*xv.w;
            acc[1][0] += wa.y*xv.x; acc[1][1] += wa.y*xv.y; acc[1][2] += wa.y*xv.z; acc[1][3] += wa.y*xv.w;
            acc[2][0] += wa.z*xv.x; acc[2][1] += wa.z*xv.y; acc[2][2] += wa.z*xv.z; acc[2][3] += wa.z*xv.w;
            acc[3][0] += wa.w*xv.x; acc[3][1] += wa.w*xv.y; acc[3][2] += wa.w*xv.z; acc[3][3] += wa.w*xv.w;
            acc[4][0] += wb.x*xv.x; acc[4][1] += wb.x*xv.y; acc[4][2] += wb.x*xv.z; acc[4][3] += wb.x*xv.w;
            acc[5][0] += wb.y*xv.x; acc[5][1] += wb.y*xv.y; acc[5][2] += wb.y*xv.z; acc[5][3] += wb.y*xv.w;
            acc[6][0] += wb.z*xv.x; acc[6][1] += wb.z*xv.y; acc[6][2] += wb.z*xv.z; acc[6][3] += wb.z*xv.w;
            acc[7][0] += wb.w*xv.x; acc[7][1] += wb.w*xv.y; acc[7][2] += wb.w*xv.z; acc[7][3] += wb.w*xv.w;
        }

        // ---- stats + window max/min ----
        float rmax[8], rmin[8];
        #pragma unroll
        for (int j = 0; j < 8; ++j) {
            float bb = bL[o2g * 8 + j];
            float vmax = -3.402823466e38f, vmin = 3.402823466e38f;
            #pragma unroll
            for (int i = 0; i < 4; ++i) {
                float v = acc[j][i] + bb;
                localS[j] += v; localQ[j] += v * v;
                vmax = fmaxf(vmax, v); vmin = fminf(vmin, v);
            }
            // reduce across the 16 lanes sharing (o2g, window)
            #pragma unroll
            for (int m = 1; m <= 8; m <<= 1) {
                vmax = fmaxf(vmax, __shfl_xor(vmax, m));
                vmin = fminf(vmin, __shfl_xor(vmin, m));
            }
            rmax[j] = vmax; rmin[j] = vmin;
        }
        {
            int winB = tile * 2 + (sg >> 4);
            int l = sg & 15;
            #pragma unroll
            for (int j = 0; j < 8; ++j) {
                long basej = ((long)(p * 64 + o2g * 8 + j) * 6 + zw) * 36 + winB;
                if (l == j)     wmaxg[basej] = rmax[j];
                if (l == 8 + j) wming[basej] = rmin[j];
            }
        }
        __syncthreads();
    }

    // ---- block-level stats reduction (32 lanes share the same o2 set) ----
    #pragma unroll
    for (int j = 0; j < 8; ++j) {
        #pragma unroll
        for (int m = 1; m <= 16; m <<= 1) {
            localS[j] += __shfl_xor(localS[j], m);
            localQ[j] += __shfl_xor(localQ[j], m);
        }
    }
    #pragma unroll
    for (int j = 0; j < 8; ++j) {
        if (sg == j)     atomicAdd(&s2sum[p * 64 + o2g * 8 + j], localS[j]);
        if (sg == 8 + j) atomicAdd(&s2sq [p * 64 + o2g * 8 + j], localQ[j]);
    }
}

// K4: finalize: apply stage-2 IN affine to window max (or min if negative scale), relu, write.
__global__ __launch_bounds__(256) void k4_final(
    const float* __restrict__ s2sum, const float* __restrict__ s2sq,
    const float* __restrict__ g_b2, const float* __restrict__ bt_b2,
    const float* __restrict__ wmaxg, const float* __restrict__ wming,
    float* __restrict__ outp)
{
    const int p = blockIdx.x;
    for (int idx = threadIdx.x; idx < 64 * 216; idx += 256) {
        int o2 = idx / 216, win = idx % 216;
        float s = s2sum[p * 64 + o2], q = s2sq[p * 64 + o2];
        float mean = s / 13824.0f;
        float var  = fmaxf(q / 13824.0f - mean * mean, 0.0f);
        float r = rsqrtf(var + EPSV);
        float sc = g_b2[o2] * r;
        float tb = bt_b2[o2] - mean * sc;
        long fi = (long)(p * 64 + o2) * 216 + win;
        float v = (sc >= 0.f) ? sc * wmaxg[fi] + tb : sc * wming[fi] + tb;
        outp[fi] = fmaxf(v, 0.0f);
    }
}

extern "C" void kernel_launch(void* const* d_in, const int* in_sizes, int n_in,
                              void* d_out, int out_size, void* d_ws, size_t ws_size,
                              hipStream_t stream)
{
    const float* out1  = (const float*)d_in[1];
    const float* comb2 = (const float*)d_in[2];
    const int*   props = (const int*)d_in[4];
    const float* w_up  = (const float*)d_in[5];
    const float* b_up  = (const float*)d_in[6];
    const float* g_up  = (const float*)d_in[7];
    const float* bt_up = (const float*)d_in[8];
    const float* w_b2  = (const float*)d_in[9];
    const float* b_b2  = (const float*)d_in[10];
    const float* g_b2  = (const float*)d_in[11];
    const float* bt_b2 = (const float*)d_in[12];
    float* outp = (float*)d_out;

    float* ws    = (float*)d_ws;
    float* y4    = ws;                      // 64*64*1728 = 7,077,888 floats
    float* a1    = y4 + 7077888;            // 4096
    float* b1    = a1 + 4096;               // 4096
    float* s2sum = b1 + 4096;               // 4096 (zeroed each call)
    float* s2sq  = s2sum + 4096;            // 4096 (zeroed each call)
    float* wmaxg = s2sq + 4096;             // 64*64*216 = 884,736
    float* wming = wmaxg + 884736;          // 884,736
    // total ~33.8 MiB

    hipMemsetAsync(s2sum, 0, 2 * 4096 * sizeof(float), stream);

    k1_conv1<<<dim3(9, NPROP), 256, 0, stream>>>(comb2, props, w_up, b_up, y4);
    k2_stats1<<<dim3(64, NPROP), 64, 0, stream>>>(y4, g_up, bt_up, a1, b1);
    k3_conv2<<<dim3(6, NPROP), 256, 0, stream>>>(y4, out1, props, a1, b1, w_b2, b_b2,
                                                 s2sum, s2sq, wmaxg, wming);
    k4_final<<<NPROP, 256, 0, stream>>>(s2sum, s2sq, g_b2, bt_b2, wmaxg, wming, outp);
}

// Round 2
// 658.592 us; speedup vs baseline: 1.5121x; 1.5121x over previous
//
#include <hip/hip_runtime.h>
#include <math.h>

// CropRoi fused pipeline, round 2: K3 rebuilt around bf16 MFMA.
// Inputs (setup_inputs order):
// 0 img (unused), 1 out1 [2,64,64,64,64], 2 comb2 [2,128,32,32,32], 3 inputs (unused),
// 4 proposals [64,7] int32, 5 w_up[64,128], 6 b_up[64], 7 g_up[64], 8 bt_up[64],
// 9 w_b2[64,128], 10 b_b2[64], 11 g_b2[64], 12 bt_b2[64]
// Output: [64,64,6,6,6] f32.

#define EPSV 1e-5f
#define NPROP 64

typedef __attribute__((ext_vector_type(8))) short bf16x8;
typedef __attribute__((ext_vector_type(4))) float f32x4;

// align_corners 2x upsample 12->24: pos = d*11/23 (mirrors JAX f32 arithmetic)
__device__ __forceinline__ void interp_idx(int d, int& i0, int& i1, float& w) {
    float pos = (float)(d * 11) / 23.0f;
    float f = floorf(pos);
    i0 = (int)f;
    i1 = min(i0 + 1, 11);
    w = pos - f;
}

__device__ __forceinline__ unsigned short f2bf(float f) {
    union { float f; unsigned u; } v; v.f = f;
    unsigned r = v.u + 0x7fffu + ((v.u >> 16) & 1u);   // RNE
    return (unsigned short)(r >> 16);
}

// K1: y4[p, o(64), site(12^3)] = sum_c comb2crop[p,c,site] * w_up[o,c] + b_up[o]
// (conv1x1 commutes with the linear upsample, so conv at low res.)
__global__ __launch_bounds__(256) void k1_conv1(
    const float* __restrict__ comb2, const int* __restrict__ props,
    const float* __restrict__ w_up, const float* __restrict__ b_up,
    float* __restrict__ y4)
{
    __shared__ float wT[128 * 64];   // wT[c*64 + o]
    __shared__ float bL[64];
    const int p = blockIdx.y;
    const int tid = threadIdx.x;
    for (int i = tid; i < 8192; i += 256) {
        int c = i >> 6, o = i & 63;
        wT[i] = w_up[o * 128 + c];
    }
    if (tid < 64) bL[tid] = b_up[tid];
    __syncthreads();

    const int b  = props[p * 7 + 0];
    const int z0 = props[p * 7 + 1] >> 2;
    const int y0 = props[p * 7 + 2] >> 2;
    const int x0 = props[p * 7 + 3] >> 2;
    const int og = tid >> 6;       // 0..3 -> o in [og*16, og*16+16)
    const int sl = tid & 63;

    for (int it = 0; it < 3; ++it) {
        int site = blockIdx.x * 192 + it * 64 + sl;   // < 1728
        int z = site / 144, rem = site % 144;
        int y = rem / 12, x = rem % 12;
        const float* src = comb2 + ((((long)b * 128) * 32 + (z0 + z)) * 32 + (y0 + y)) * 32 + (x0 + x);

        float acc[16];
        #pragma unroll
        for (int j = 0; j < 16; ++j) acc[j] = bL[og * 16 + j];

        for (int c = 0; c < 128; ++c) {
            float v = src[c * 32768];
            const float4* wv = (const float4*)&wT[c * 64 + og * 16];
            float4 w0 = wv[0], w1 = wv[1], w2 = wv[2], w3 = wv[3];
            acc[0]  += v * w0.x; acc[1]  += v * w0.y; acc[2]  += v * w0.z; acc[3]  += v * w0.w;
            acc[4]  += v * w1.x; acc[5]  += v * w1.y; acc[6]  += v * w1.z; acc[7]  += v * w1.w;
            acc[8]  += v * w2.x; acc[9]  += v * w2.y; acc[10] += v * w2.z; acc[11] += v * w2.w;
            acc[12] += v * w3.x; acc[13] += v * w3.y; acc[14] += v * w3.z; acc[15] += v * w3.w;
        }
        long obase = ((long)p * 64 + og * 16) * 1728 + site;
        #pragma unroll
        for (int j = 0; j < 16; ++j) y4[obase + (long)j * 1728] = acc[j];
    }
}

// K2: per (p,c) stats of the upsampled (24^3) field -> affine a1,b1 for stage-1 IN.
__global__ __launch_bounds__(256) void k2_stats1(
    const float* __restrict__ y4, const float* __restrict__ g_up,
    const float* __restrict__ bt_up, float* __restrict__ a1, float* __restrict__ b1)
{
    __shared__ float ch[1728];
    __shared__ float red[8];
    const int c = blockIdx.x, p = blockIdx.y;
    const int tid = threadIdx.x;
    const float* src = y4 + ((long)p * 64 + c) * 1728;
    for (int i = tid; i < 1728; i += 256) ch[i] = src[i];
    __syncthreads();

    float sum = 0.f, sq = 0.f;
    for (int s = tid; s < 13824; s += 256) {
        int z = s / 576, rem = s % 576;
        int y = rem / 24, x = rem % 24;
        int iz0, iz1, iy0, iy1, ix0, ix1; float wz, wy, wx;
        interp_idx(z, iz0, iz1, wz);
        interp_idx(y, iy0, iy1, wy);
        interp_idx(x, ix0, ix1, wx);
        float v00 = ch[iz0*144 + iy0*12 + ix0] * (1.f - wx) + ch[iz0*144 + iy0*12 + ix1] * wx;
        float v01 = ch[iz0*144 + iy1*12 + ix0] * (1.f - wx) + ch[iz0*144 + iy1*12 + ix1] * wx;
        float v10 = ch[iz1*144 + iy0*12 + ix0] * (1.f - wx) + ch[iz1*144 + iy0*12 + ix1] * wx;
        float v11 = ch[iz1*144 + iy1*12 + ix0] * (1.f - wx) + ch[iz1*144 + iy1*12 + ix1] * wx;
        float v0 = v00 * (1.f - wy) + v01 * wy;
        float v1 = v10 * (1.f - wy) + v11 * wy;
        float u  = v0  * (1.f - wz) + v1  * wz;
        sum += u; sq += u * u;
    }
    #pragma unroll
    for (int m = 32; m >= 1; m >>= 1) { sum += __shfl_xor(sum, m); sq += __shfl_xor(sq, m); }
    if ((tid & 63) == 0) { red[(tid >> 6) * 2] = sum; red[(tid >> 6) * 2 + 1] = sq; }
    __syncthreads();
    if (tid == 0) {
        sum = red[0] + red[2] + red[4] + red[6];
        sq  = red[1] + red[3] + red[5] + red[7];
        float mean = sum / 13824.0f;
        float var  = fmaxf(sq / 13824.0f - mean * mean, 0.0f);
        float r = rsqrtf(var + EPSV);
        float a = g_up[c] * r;
        a1[p * 64 + c] = a;
        b1[p * 64 + c] = bt_up[c] - mean * a;
    }
}

// K3: fused conv2 (bf16 MFMA) + stage-2 stats + per-window max/min.
// Grid (12, 64): blockIdx.x -> (zw = bx>>1, h = bx&1); each block does 9 window-pairs
// (128 sites each) of its z-slab half. 256 threads = 4 waves; wave w owns o2 [w*16,w*16+16).
__global__ __launch_bounds__(256) void k3_conv2(
    const float* __restrict__ y4, const float* __restrict__ out1,
    const int* __restrict__ props,
    const float* __restrict__ a1, const float* __restrict__ b1,
    const float* __restrict__ w_b2, const float* __restrict__ b_b2,
    float* __restrict__ s2sum, float* __restrict__ s2sq,
    float* __restrict__ wmaxg, float* __restrict__ wming)
{
    // Xin[site][k] bf16, row = 256B, byte-XOR-swizzled by (site&7)<<4 (T2).
    __shared__ __align__(16) char XinB[128 * 256];
    __shared__ float a1L[64], b1L[64];

    const int bx = blockIdx.x, p = blockIdx.y;
    const int zw = bx >> 1, h = bx & 1;
    const int tid = threadIdx.x;
    const int w = tid >> 6, l = tid & 63;

    if (tid < 64) { a1L[tid] = a1[p * 64 + tid]; b1L[tid] = b1[p * 64 + tid]; }

    const int bidx = props[p * 7 + 0];
    const int z2 = props[p * 7 + 1] >> 1;
    const int y2 = props[p * 7 + 2] >> 1;
    const int x2 = props[p * 7 + 3] >> 1;
    const float* y4p = y4 + (long)p * 64 * 1728;

    // ---- Phase-A identity (all 256 threads stage): site + channel-half ----
    const int siteA = tid & 127, chHalf = tid >> 7;   // chHalf: 32 channels each
    const int whA = siteA >> 6, widxA = siteA & 63;
    const int zlA = widxA >> 4, ylA = (widxA >> 2) & 3, xlA = widxA & 3;
    const int zgA = zw * 4 + zlA;
    int iz0, iz1; float wz; interp_idx(zgA, iz0, iz1, wz);
    const int cb = chHalf * 32;                       // channel base for this thread

    // ---- Phase-B identity: A-fragments (weights) once, from global ----
    const int g = l >> 4;                 // k-group
    const int o2a = (w << 4) + (l & 15);  // A-operand row
    bf16x8 afr[4];
    #pragma unroll
    for (int kk = 0; kk < 4; ++kk) {
        const float* wp = w_b2 + o2a * 128 + kk * 32 + g * 8;
        #pragma unroll
        for (int j = 0; j < 8; ++j) afr[kk][j] = (short)f2bf(wp[j]);
    }
    float bb[4];
    #pragma unroll
    for (int j = 0; j < 4; ++j) bb[j] = b_b2[(w << 4) + g * 4 + j];   // D rows

    float lS[4] = {0,0,0,0}, lQ[4] = {0,0,0,0};
    __syncthreads();   // a1L/b1L ready

    for (int t = 0; t < 9; ++t) {
        // ================= Phase A: stage Xin (bf16) =================
        {
            int win = (h * 9 + t) * 2 + whA;          // 0..35 within slab
            int yw = win / 6, xw = win % 6;
            int yg = yw * 4 + ylA, xg = xw * 4 + xlA;
            int iy0, iy1, ix0, ix1; float wy, wx;
            interp_idx(yg, iy0, iy1, wy);
            interp_idx(xg, ix0, ix1, wx);
            float wz0 = 1.f - wz, wy0 = 1.f - wy, wx0 = 1.f - wx;
            float w000 = wz0*wy0*wx0, w001 = wz0*wy0*wx, w010 = wz0*wy*wx0, w011 = wz0*wy*wx;
            float w100 = wz*wy0*wx0,  w101 = wz*wy0*wx,  w110 = wz*wy*wx0,  w111 = wz*wy*wx;
            int o000 = iz0*144 + iy0*12 + ix0, o001 = iz0*144 + iy0*12 + ix1;
            int o010 = iz0*144 + iy1*12 + ix0, o011 = iz0*144 + iy1*12 + ix1;
            int o100 = iz1*144 + iy0*12 + ix0, o101 = iz1*144 + iy0*12 + ix1;
            int o110 = iz1*144 + iy1*12 + ix0, o111 = iz1*144 + iy1*12 + ix1;

            const int rowOff = siteA << 8;
            const int sw = (siteA & 7) << 4;

            // 32 channels of upsample -> relu(IN) -> bf16 (k = cb..cb+32)
            #pragma unroll
            for (int cg = 0; cg < 4; ++cg) {
                unsigned pk[4];
                #pragma unroll
                for (int u = 0; u < 8; u += 2) {
                    float vv[2];
                    #pragma unroll
                    for (int q = 0; q < 2; ++q) {
                        int c = cb + cg * 8 + u + q;
                        const float* chp = y4p + c * 1728;
                        float uv = w000*chp[o000] + w001*chp[o001] + w010*chp[o010] + w011*chp[o011]
                                 + w100*chp[o100] + w101*chp[o101] + w110*chp[o110] + w111*chp[o111];
                        vv[q] = fmaxf(a1L[c] * uv + b1L[c], 0.0f);
                    }
                    pk[u >> 1] = (unsigned)f2bf(vv[0]) | ((unsigned)f2bf(vv[1]) << 16);
                }
                int kbyte = (cb + cg * 8) * 2;
                *(uint4*)(XinB + rowOff + (kbyte ^ sw)) = make_uint4(pk[0], pk[1], pk[2], pk[3]);
            }
            // 32 channels of out1 crop -> bf16 (k = 64+cb .. 64+cb+32)
            const float* o1p = out1 + ((((long)bidx * 64 + cb) * 64 + (z2 + zgA)) * 64 + (y2 + yg)) * 64 + (x2 + xg);
            #pragma unroll
            for (int cg = 0; cg < 4; ++cg) {
                unsigned pk[4];
                #pragma unroll
                for (int u = 0; u < 8; u += 2) {
                    float v0 = o1p[(long)(cg * 8 + u) * 262144];
                    float v1 = o1p[(long)(cg * 8 + u + 1) * 262144];
                    pk[u >> 1] = (unsigned)f2bf(v0) | ((unsigned)f2bf(v1) << 16);
                }
                int kbyte = 128 + (cb + cg * 8) * 2;
                *(uint4*)(XinB + rowOff + (kbyte ^ sw)) = make_uint4(pk[0], pk[1], pk[2], pk[3]);
            }
        }
        __syncthreads();

        // ================= Phase B: MFMA over 8 site-tiles =================
        float vmx[2][4], vmn[2][4];
        #pragma unroll
        for (int q = 0; q < 4; ++q) {
            vmx[0][q] = vmx[1][q] = -3.402823466e38f;
            vmn[0][q] = vmn[1][q] =  3.402823466e38f;
        }

        #pragma unroll
        for (int st = 0; st < 8; ++st) {
            const int srow = st * 16 + (l & 15);
            const int sOff = (srow << 8);
            const int ssw = (srow & 7) << 4;
            bf16x8 bfr[4];
            #pragma unroll
            for (int kk = 0; kk < 4; ++kk) {
                int kbyte = kk * 64 + g * 16;
                bfr[kk] = *(const bf16x8*)(XinB + sOff + (kbyte ^ ssw));
            }
            f32x4 acc = {0.f, 0.f, 0.f, 0.f};
            #pragma unroll
            for (int kk = 0; kk < 4; ++kk)
                acc = __builtin_amdgcn_mfma_f32_16x16x32_bf16(afr[kk], bfr[kk], acc, 0, 0, 0);

            const int wh = st >> 2;
            #pragma unroll
            for (int j = 0; j < 4; ++j) {
                float v = acc[j] + bb[j];
                lS[j] += v; lQ[j] += v * v;
                vmx[wh][j] = fmaxf(vmx[wh][j], v);
                vmn[wh][j] = fminf(vmn[wh][j], v);
            }
        }

        // window reduce across the 16 site-columns
        #pragma unroll
        for (int wh = 0; wh < 2; ++wh)
            #pragma unroll
            for (int j = 0; j < 4; ++j) {
                float mx = vmx[wh][j], mn = vmn[wh][j];
                #pragma unroll
                for (int m = 1; m <= 8; m <<= 1) {
                    mx = fmaxf(mx, __shfl_xor(mx, m));
                    mn = fminf(mn, __shfl_xor(mn, m));
                }
                vmx[wh][j] = mx; vmn[wh][j] = mn;
            }
        if ((l & 15) == 0) {
            #pragma unroll
            for (int wh = 0; wh < 2; ++wh) {
                int win = (h * 9 + t) * 2 + wh;
                #pragma unroll
                for (int j = 0; j < 4; ++j) {
                    int o2d = (w << 4) + g * 4 + j;
                    long idx = ((long)(p * 64 + o2d) * 6 + zw) * 36 + win;
                    wmaxg[idx] = vmx[wh][j];
                    wming[idx] = vmn[wh][j];
                }
            }
        }
        __syncthreads();
    }

    // ---- stats reduction across the 16 site-columns, then atomics ----
    #pragma unroll
    for (int j = 0; j < 4; ++j) {
        #pragma unroll
        for (int m = 1; m <= 8; m <<= 1) {
            lS[j] += __shfl_xor(lS[j], m);
            lQ[j] += __shfl_xor(lQ[j], m);
        }
    }
    if ((l & 15) == 0) {
        #pragma unroll
        for (int j = 0; j < 4; ++j) {
            int o2d = (w << 4) + g * 4 + j;
            atomicAdd(&s2sum[p * 64 + o2d], lS[j]);
            atomicAdd(&s2sq [p * 64 + o2d], lQ[j]);
        }
    }
}

// K4: finalize: apply stage-2 IN affine to window max (or min if negative scale), relu, write.
__global__ __launch_bounds__(256) void k4_final(
    const float* __restrict__ s2sum, const float* __restrict__ s2sq,
    const float* __restrict__ g_b2, const float* __restrict__ bt_b2,
    const float* __restrict__ wmaxg, const float* __restrict__ wming,
    float* __restrict__ outp)
{
    const int p = blockIdx.x;
    for (int idx = threadIdx.x; idx < 64 * 216; idx += 256) {
        int o2 = idx / 216, win = idx % 216;
        float s = s2sum[p * 64 + o2], q = s2sq[p * 64 + o2];
        float mean = s / 13824.0f;
        float var  = fmaxf(q / 13824.0f - mean * mean, 0.0f);
        float r = rsqrtf(var + EPSV);
        float sc = g_b2[o2] * r;
        float tb = bt_b2[o2] - mean * sc;
        long fi = (long)(p * 64 + o2) * 216 + win;
        float v = (sc >= 0.f) ? sc * wmaxg[fi] + tb : sc * wming[fi] + tb;
        outp[fi] = fmaxf(v, 0.0f);
    }
}

extern "C" void kernel_launch(void* const* d_in, const int* in_sizes, int n_in,
                              void* d_out, int out_size, void* d_ws, size_t ws_size,
                              hipStream_t stream)
{
    const float* out1  = (const float*)d_in[1];
    const float* comb2 = (const float*)d_in[2];
    const int*   props = (const int*)d_in[4];
    const float* w_up  = (const float*)d_in[5];
    const float* b_up  = (const float*)d_in[6];
    const float* g_up  = (const float*)d_in[7];
    const float* bt_up = (const float*)d_in[8];
    const float* w_b2  = (const float*)d_in[9];
    const float* b_b2  = (const float*)d_in[10];
    const float* g_b2  = (const float*)d_in[11];
    const float* bt_b2 = (const float*)d_in[12];
    float* outp = (float*)d_out;

    float* ws    = (float*)d_ws;
    float* y4    = ws;                      // 64*64*1728 = 7,077,888 floats
    float* a1    = y4 + 7077888;            // 4096
    float* b1    = a1 + 4096;               // 4096
    float* s2sum = b1 + 4096;               // 4096 (zeroed each call)
    float* s2sq  = s2sum + 4096;            // 4096 (zeroed each call)
    float* wmaxg = s2sq + 4096;             // 64*64*216 = 884,736
    float* wming = wmaxg + 884736;          // 884,736
    // total ~33.8 MiB

    hipMemsetAsync(s2sum, 0, 2 * 4096 * sizeof(float), stream);

    k1_conv1<<<dim3(9, NPROP), 256, 0, stream>>>(comb2, props, w_up, b_up, y4);
    k2_stats1<<<dim3(64, NPROP), 256, 0, stream>>>(y4, g_up, bt_up, a1, b1);
    k3_conv2<<<dim3(12, NPROP), 256, 0, stream>>>(y4, out1, props, a1, b1, w_b2, b_b2,
                                                  s2sum, s2sq, wmaxg, wming);
    k4_final<<<NPROP, 256, 0, stream>>>(s2sum, s2sq, g_b2, bt_b2, wmaxg, wming, outp);
}

// Round 3
// 531.196 us; speedup vs baseline: 1.8747x; 1.2398x over previous
//
#include <hip/hip_runtime.h>
#include <math.h>

// CropRoi fused pipeline, round 3: site-major y4 + vectorized K3 staging.
// Inputs (setup_inputs order):
// 0 img (unused), 1 out1 [2,64,64,64,64], 2 comb2 [2,128,32,32,32], 3 inputs (unused),
// 4 proposals [64,7] int32, 5 w_up[64,128], 6 b_up[64], 7 g_up[64], 8 bt_up[64],
// 9 w_b2[64,128], 10 b_b2[64], 11 g_b2[64], 12 bt_b2[64]
// Output: [64,64,6,6,6] f32.

#define EPSV 1e-5f
#define NPROP 64

typedef __attribute__((ext_vector_type(8))) short bf16x8;
typedef __attribute__((ext_vector_type(4))) float f32x4;

// align_corners 2x upsample 12->24: pos = d*11/23 (mirrors JAX f32 arithmetic)
__device__ __forceinline__ void interp_idx(int d, int& i0, int& i1, float& w) {
    float pos = (float)(d * 11) / 23.0f;
    float f = floorf(pos);
    i0 = (int)f;
    i1 = min(i0 + 1, 11);
    w = pos - f;
}

__device__ __forceinline__ unsigned short f2bf(float f) {
    union { float f; unsigned u; } v; v.f = f;
    unsigned r = v.u + 0x7fffu + ((v.u >> 16) & 1u);   // RNE
    return (unsigned short)(r >> 16);
}

// K1: y4s[p][site(12^3)][o(64)] = conv1x1(comb2 crop) — SITE-MAJOR output.
__global__ __launch_bounds__(256) void k1_conv1(
    const float* __restrict__ comb2, const int* __restrict__ props,
    const float* __restrict__ w_up, const float* __restrict__ b_up,
    float* __restrict__ y4s)
{
    __shared__ float wT[128 * 64];   // wT[c*64 + o]
    __shared__ float bL[64];
    const int p = blockIdx.y;
    const int tid = threadIdx.x;
    for (int i = tid; i < 8192; i += 256) {
        int c = i >> 6, o = i & 63;
        wT[i] = w_up[o * 128 + c];
    }
    if (tid < 64) bL[tid] = b_up[tid];
    __syncthreads();

    const int b  = props[p * 7 + 0];
    const int z0 = props[p * 7 + 1] >> 2;
    const int y0 = props[p * 7 + 2] >> 2;
    const int x0 = props[p * 7 + 3] >> 2;
    const int og = tid >> 6;       // 0..3 -> o in [og*16, og*16+16)
    const int sl = tid & 63;

    for (int it = 0; it < 3; ++it) {
        int site = blockIdx.x * 192 + it * 64 + sl;   // < 1728
        int z = site / 144, rem = site % 144;
        int y = rem / 12, x = rem % 12;
        const float* src = comb2 + ((((long)b * 128) * 32 + (z0 + z)) * 32 + (y0 + y)) * 32 + (x0 + x);

        float acc[16];
        #pragma unroll
        for (int j = 0; j < 16; ++j) acc[j] = bL[og * 16 + j];

        for (int c = 0; c < 128; ++c) {
            float v = src[c * 32768];
            const float4* wv = (const float4*)&wT[c * 64 + og * 16];
            float4 w0 = wv[0], w1 = wv[1], w2 = wv[2], w3 = wv[3];
            acc[0]  += v * w0.x; acc[1]  += v * w0.y; acc[2]  += v * w0.z; acc[3]  += v * w0.w;
            acc[4]  += v * w1.x; acc[5]  += v * w1.y; acc[6]  += v * w1.z; acc[7]  += v * w1.w;
            acc[8]  += v * w2.x; acc[9]  += v * w2.y; acc[10] += v * w2.z; acc[11] += v * w2.w;
            acc[12] += v * w3.x; acc[13] += v * w3.y; acc[14] += v * w3.z; acc[15] += v * w3.w;
        }
        float* dst = y4s + ((long)p * 1728 + site) * 64 + og * 16;
        #pragma unroll
        for (int j = 0; j < 16; j += 4)
            *(float4*)(dst + j) = make_float4(acc[j], acc[j+1], acc[j+2], acc[j+3]);
    }
}

// K2: per (p,c) stats of the upsampled (24^3) field -> affine a1,b1 for stage-1 IN.
// Reads channel c strided from site-major y4s (L2/L3-resident; 28 MB total).
__global__ __launch_bounds__(256) void k2_stats1(
    const float* __restrict__ y4s, const float* __restrict__ g_up,
    const float* __restrict__ bt_up, float* __restrict__ a1, float* __restrict__ b1)
{
    __shared__ float ch[1728];
    __shared__ float red[8];
    const int c = blockIdx.x, p = blockIdx.y;
    const int tid = threadIdx.x;
    const float* src = y4s + (long)p * 110592 + c;
    for (int i = tid; i < 1728; i += 256) ch[i] = src[(long)i * 64];
    __syncthreads();

    float sum = 0.f, sq = 0.f;
    for (int s = tid; s < 13824; s += 256) {
        int z = s / 576, rem = s % 576;
        int y = rem / 24, x = rem % 24;
        int iz0, iz1, iy0, iy1, ix0, ix1; float wz, wy, wx;
        interp_idx(z, iz0, iz1, wz);
        interp_idx(y, iy0, iy1, wy);
        interp_idx(x, ix0, ix1, wx);
        float v00 = ch[iz0*144 + iy0*12 + ix0] * (1.f - wx) + ch[iz0*144 + iy0*12 + ix1] * wx;
        float v01 = ch[iz0*144 + iy1*12 + ix0] * (1.f - wx) + ch[iz0*144 + iy1*12 + ix1] * wx;
        float v10 = ch[iz1*144 + iy0*12 + ix0] * (1.f - wx) + ch[iz1*144 + iy0*12 + ix1] * wx;
        float v11 = ch[iz1*144 + iy1*12 + ix0] * (1.f - wx) + ch[iz1*144 + iy1*12 + ix1] * wx;
        float v0 = v00 * (1.f - wy) + v01 * wy;
        float v1 = v10 * (1.f - wy) + v11 * wy;
        float u  = v0  * (1.f - wz) + v1  * wz;
        sum += u; sq += u * u;
    }
    #pragma unroll
    for (int m = 32; m >= 1; m >>= 1) { sum += __shfl_xor(sum, m); sq += __shfl_xor(sq, m); }
    if ((tid & 63) == 0) { red[(tid >> 6) * 2] = sum; red[(tid >> 6) * 2 + 1] = sq; }
    __syncthreads();
    if (tid == 0) {
        sum = red[0] + red[2] + red[4] + red[6];
        sq  = red[1] + red[3] + red[5] + red[7];
        float mean = sum / 13824.0f;
        float var  = fmaxf(sq / 13824.0f - mean * mean, 0.0f);
        float r = rsqrtf(var + EPSV);
        float a = g_up[c] * r;
        a1[p * 64 + c] = a;
        b1[p * 64 + c] = bt_up[c] - mean * a;
    }
}

// K3: fused conv2 (bf16 MFMA) + stage-2 stats + per-window max/min.
// Grid (108, 64): bx -> zw = bx/18 (z-slab), tw = bx%18 (window-pair). One 128-site
// tile per block. Staging: waves 0-1 compute x1 atoms (8ch x 1site, vector taps from
// site-major y4s); waves 2-3 pack out1 crop. Phase B identical to the verified R2 code.
__global__ __launch_bounds__(256) void k3_conv2(
    const float* __restrict__ y4s, const float* __restrict__ out1,
    const int* __restrict__ props,
    const float* __restrict__ a1, const float* __restrict__ b1,
    const float* __restrict__ w_b2, const float* __restrict__ b_b2,
    float* __restrict__ s2sum, float* __restrict__ s2sq,
    float* __restrict__ wmaxg, float* __restrict__ wming)
{
    // Xin[site][k] bf16, row = 256B, byte-XOR-swizzled by (site&7)<<4 (T2).
    __shared__ __align__(16) char XinB[128 * 256];
    __shared__ float a1L[64], b1L[64];

    const int bx = blockIdx.x, p = blockIdx.y;
    const int zw = bx / 18, tw = bx % 18;
    const int tid = threadIdx.x;
    const int w = tid >> 6, l = tid & 63;

    if (tid < 64) { a1L[tid] = a1[p * 64 + tid]; b1L[tid] = b1[p * 64 + tid]; }

    const int bidx = props[p * 7 + 0];
    const int z2 = props[p * 7 + 1] >> 1;
    const int y2 = props[p * 7 + 2] >> 1;
    const int x2 = props[p * 7 + 3] >> 1;
    const float* y4sp = y4s + (long)p * 110592;

    // ---- Phase-B A-fragments (weights) from global, bf16 ----
    const int g = l >> 4;                 // k-group
    const int o2a = (w << 4) + (l & 15);  // A-operand row
    bf16x8 afr[4];
    #pragma unroll
    for (int kk = 0; kk < 4; ++kk) {
        const float* wp = w_b2 + o2a * 128 + kk * 32 + g * 8;
        #pragma unroll
        for (int j = 0; j < 8; ++j) afr[kk][j] = (short)f2bf(wp[j]);
    }
    float bb[4];
    #pragma unroll
    for (int j = 0; j < 4; ++j) bb[j] = b_b2[(w << 4) + g * 4 + j];   // D rows

    __syncthreads();   // a1L/b1L ready

    // ================= Phase A: stage Xin (bf16) =================
    {
        const int site = tid & 127;
        const int wh = site >> 6, widx = site & 63;
        const int zl = widx >> 4, yl = (widx >> 2) & 3, xl = widx & 3;
        const int w36 = tw * 2 + wh;
        const int yw = w36 / 6, xw = w36 % 6;
        const int zg = zw * 4 + zl, yg = yw * 4 + yl, xg = xw * 4 + xl;
        const int rowOff = site << 8;
        const int sw = (site & 7) << 4;

        if (tid < 128) {
            // x1 half: 8 chunks of 8 channels via trilinear taps from y4s rows
            int iz0, iz1, iy0, iy1, ix0, ix1; float wz, wy, wx;
            interp_idx(zg, iz0, iz1, wz);
            interp_idx(yg, iy0, iy1, wy);
            interp_idx(xg, ix0, ix1, wx);
            float wz0 = 1.f - wz, wy0 = 1.f - wy, wx0 = 1.f - wx;
            float tw8[8] = { wz0*wy0*wx0, wz0*wy0*wx, wz0*wy*wx0, wz0*wy*wx,
                             wz*wy0*wx0,  wz*wy0*wx,  wz*wy*wx0,  wz*wy*wx };
            int to8[8] = { (iz0*144+iy0*12+ix0)*64, (iz0*144+iy0*12+ix1)*64,
                           (iz0*144+iy1*12+ix0)*64, (iz0*144+iy1*12+ix1)*64,
                           (iz1*144+iy0*12+ix0)*64, (iz1*144+iy0*12+ix1)*64,
                           (iz1*144+iy1*12+ix0)*64, (iz1*144+iy1*12+ix1)*64 };
            for (int chunk = 0; chunk < 8; ++chunk) {
                const int c0 = chunk * 8;
                float u[8] = {0,0,0,0,0,0,0,0};
                #pragma unroll
                for (int t = 0; t < 8; ++t) {
                    const float* tp = y4sp + to8[t] + c0;
                    float4 va = *(const float4*)tp;
                    float4 vb = *(const float4*)(tp + 4);
                    float wt = tw8[t];
                    u[0] += wt * va.x; u[1] += wt * va.y; u[2] += wt * va.z; u[3] += wt * va.w;
                    u[4] += wt * vb.x; u[5] += wt * vb.y; u[6] += wt * vb.z; u[7] += wt * vb.w;
                }
                unsigned pk[4];
                #pragma unroll
                for (int q = 0; q < 8; q += 2) {
                    float va = fmaxf(a1L[c0+q]   * u[q]   + b1L[c0+q],   0.0f);
                    float vb = fmaxf(a1L[c0+q+1] * u[q+1] + b1L[c0+q+1], 0.0f);
                    pk[q >> 1] = (unsigned)f2bf(va) | ((unsigned)f2bf(vb) << 16);
                }
                *(uint4*)(XinB + rowOff + ((chunk * 16) ^ sw)) = make_uint4(pk[0], pk[1], pk[2], pk[3]);
            }
        } else {
            // out1 half: 16 iterations of 4 channels
            const float* o1p = out1 + ((((long)bidx * 64) * 64 + (z2 + zg)) * 64 + (y2 + yg)) * 64 + (x2 + xg);
            for (int it = 0; it < 16; ++it) {
                float v0 = o1p[(long)(it*4+0) * 262144];
                float v1 = o1p[(long)(it*4+1) * 262144];
                float v2 = o1p[(long)(it*4+2) * 262144];
                float v3 = o1p[(long)(it*4+3) * 262144];
                unsigned lo = (unsigned)f2bf(v0) | ((unsigned)f2bf(v1) << 16);
                unsigned hi = (unsigned)f2bf(v2) | ((unsigned)f2bf(v3) << 16);
                *(uint2*)(XinB + rowOff + ((128 + it * 8) ^ sw)) = make_uint2(lo, hi);
            }
        }
    }
    __syncthreads();

    // ================= Phase B: MFMA over 8 site-tiles =================
    float lS[4] = {0,0,0,0}, lQ[4] = {0,0,0,0};
    float vmx[2][4], vmn[2][4];
    #pragma unroll
    for (int q = 0; q < 4; ++q) {
        vmx[0][q] = vmx[1][q] = -3.402823466e38f;
        vmn[0][q] = vmn[1][q] =  3.402823466e38f;
    }

    #pragma unroll
    for (int st = 0; st < 8; ++st) {
        const int srow = st * 16 + (l & 15);
        const int sOff = (srow << 8);
        const int ssw = (srow & 7) << 4;
        bf16x8 bfr[4];
        #pragma unroll
        for (int kk = 0; kk < 4; ++kk) {
            int kbyte = kk * 64 + g * 16;
            bfr[kk] = *(const bf16x8*)(XinB + sOff + (kbyte ^ ssw));
        }
        f32x4 acc = {0.f, 0.f, 0.f, 0.f};
        #pragma unroll
        for (int kk = 0; kk < 4; ++kk)
            acc = __builtin_amdgcn_mfma_f32_16x16x32_bf16(afr[kk], bfr[kk], acc, 0, 0, 0);

        const int wh = st >> 2;
        #pragma unroll
        for (int j = 0; j < 4; ++j) {
            float v = acc[j] + bb[j];
            lS[j] += v; lQ[j] += v * v;
            vmx[wh][j] = fmaxf(vmx[wh][j], v);
            vmn[wh][j] = fminf(vmn[wh][j], v);
        }
    }

    // window reduce across the 16 site-columns
    #pragma unroll
    for (int wh = 0; wh < 2; ++wh)
        #pragma unroll
        for (int j = 0; j < 4; ++j) {
            float mx = vmx[wh][j], mn = vmn[wh][j];
            #pragma unroll
            for (int m = 1; m <= 8; m <<= 1) {
                mx = fmaxf(mx, __shfl_xor(mx, m));
                mn = fminf(mn, __shfl_xor(mn, m));
            }
            vmx[wh][j] = mx; vmn[wh][j] = mn;
        }
    if ((l & 15) == 0) {
        #pragma unroll
        for (int wh = 0; wh < 2; ++wh) {
            int win = (tw * 2 + wh);
            #pragma unroll
            for (int j = 0; j < 4; ++j) {
                int o2d = (w << 4) + g * 4 + j;
                long idx = ((long)(p * 64 + o2d) * 6 + zw) * 36 + win;
                wmaxg[idx] = vmx[wh][j];
                wming[idx] = vmn[wh][j];
            }
        }
    }

    // ---- stats reduction across the 16 site-columns, then atomics ----
    #pragma unroll
    for (int j = 0; j < 4; ++j) {
        #pragma unroll
        for (int m = 1; m <= 8; m <<= 1) {
            lS[j] += __shfl_xor(lS[j], m);
            lQ[j] += __shfl_xor(lQ[j], m);
        }
    }
    if ((l & 15) == 0) {
        #pragma unroll
        for (int j = 0; j < 4; ++j) {
            int o2d = (w << 4) + g * 4 + j;
            atomicAdd(&s2sum[p * 64 + o2d], lS[j]);
            atomicAdd(&s2sq [p * 64 + o2d], lQ[j]);
        }
    }
}

// K4: finalize: apply stage-2 IN affine to window max (or min if negative scale), relu, write.
__global__ __launch_bounds__(256) void k4_final(
    const float* __restrict__ s2sum, const float* __restrict__ s2sq,
    const float* __restrict__ g_b2, const float* __restrict__ bt_b2,
    const float* __restrict__ wmaxg, const float* __restrict__ wming,
    float* __restrict__ outp)
{
    const int p = blockIdx.x;
    for (int idx = threadIdx.x; idx < 64 * 216; idx += 256) {
        int o2 = idx / 216, win = idx % 216;
        float s = s2sum[p * 64 + o2], q = s2sq[p * 64 + o2];
        float mean = s / 13824.0f;
        float var  = fmaxf(q / 13824.0f - mean * mean, 0.0f);
        float r = rsqrtf(var + EPSV);
        float sc = g_b2[o2] * r;
        float tb = bt_b2[o2] - mean * sc;
        long fi = (long)(p * 64 + o2) * 216 + win;
        float v = (sc >= 0.f) ? sc * wmaxg[fi] + tb : sc * wming[fi] + tb;
        outp[fi] = fmaxf(v, 0.0f);
    }
}

extern "C" void kernel_launch(void* const* d_in, const int* in_sizes, int n_in,
                              void* d_out, int out_size, void* d_ws, size_t ws_size,
                              hipStream_t stream)
{
    const float* out1  = (const float*)d_in[1];
    const float* comb2 = (const float*)d_in[2];
    const int*   props = (const int*)d_in[4];
    const float* w_up  = (const float*)d_in[5];
    const float* b_up  = (const float*)d_in[6];
    const float* g_up  = (const float*)d_in[7];
    const float* bt_up = (const float*)d_in[8];
    const float* w_b2  = (const float*)d_in[9];
    const float* b_b2  = (const float*)d_in[10];
    const float* g_b2  = (const float*)d_in[11];
    const float* bt_b2 = (const float*)d_in[12];
    float* outp = (float*)d_out;

    float* ws    = (float*)d_ws;
    float* y4s   = ws;                      // 64*1728*64 = 7,077,888 floats (site-major)
    float* a1    = y4s + 7077888;           // 4096
    float* b1    = a1 + 4096;               // 4096
    float* s2sum = b1 + 4096;               // 4096 (zeroed each call)
    float* s2sq  = s2sum + 4096;            // 4096 (zeroed each call)
    float* wmaxg = s2sq + 4096;             // 64*64*216 = 884,736
    float* wming = wmaxg + 884736;          // 884,736
    // total ~33.9 MiB

    hipMemsetAsync(s2sum, 0, 2 * 4096 * sizeof(float), stream);

    k1_conv1<<<dim3(9, NPROP), 256, 0, stream>>>(comb2, props, w_up, b_up, y4s);
    k2_stats1<<<dim3(64, NPROP), 256, 0, stream>>>(y4s, g_up, bt_up, a1, b1);
    k3_conv2<<<dim3(108, NPROP), 256, 0, stream>>>(y4s, out1, props, a1, b1, w_b2, b_b2,
                                                   s2sum, s2sq, wmaxg, wming);
    k4_final<<<NPROP, 256, 0, stream>>>(s2sum, s2sq, g_b2, bt_b2, wmaxg, wming, outp);
}